// Round 2
// baseline (170.925 us; speedup 1.0000x reference)
//
#include <hip/hip_runtime.h>

typedef __attribute__((ext_vector_type(4))) float f32x4;
typedef __attribute__((ext_vector_type(8))) __bf16 bf16x8;

#define NCTX 8192
#define NH 32
#define DH 128
#define ROWE (NH*DH)                 /* 4096 floats between consecutive positions */
#define SCALE 0.08838834764831845f   /* 1/sqrt(128) */
#define PSTR 40                      /* P lds row stride (bf16): 80B, 16B-aligned, 2-way-bank-free */

__device__ __forceinline__ unsigned f2bf(float x) {
  union { float f; unsigned u; } un; un.f = x;
  return (un.u + 0x7FFFu + ((un.u >> 16) & 1u)) >> 16;   // RNE f32->bf16 bits
}
__device__ __forceinline__ unsigned pk2(float a, float b) {
  return f2bf(a) | (f2bf(b) << 16);
}

// One wave per sequence position: 32(heads) x 32(heads) attention, d=128.
__global__ __launch_bounds__(512, 2) void hda(
    const float* __restrict__ q, const float* __restrict__ kg,
    const float* __restrict__ v, float* __restrict__ out)
{
  __shared__ __align__(16) unsigned short Pl[8][32][PSTR];  // per-wave normalized P (bf16)

  const int tid  = threadIdx.x;
  const int w    = tid >> 6;
  const int lane = tid & 63;
  const int c = lane & 15;    // frag row/col index
  const int g = lane >> 4;    // lane group 0..3

  const int pos = blockIdx.x * 8 + w;         // 0..16383
  const int b = pos >> 13;
  const int s = pos & (NCTX - 1);
  const int r = min(4 * s, NCTX - 1);         // dilated+clamped K/V position

  const float* qp = q  + ((size_t)b * NCTX + s) * ROWE;
  const float* kp = kg + ((size_t)b * NCTX + r) * ROWE;
  const float* vp = v  + ((size_t)b * NCTX + r) * ROWE;
  float*       op = out + ((size_t)b * NCTX + s) * ROWE;

  // ---- Q A-frags / K B-frags: lane holds row (t*16+c), d = ks*32 + g*8 .. +7
  bf16x8 qa[2][4], kb[2][4];
#pragma unroll
  for (int t = 0; t < 2; ++t) {
#pragma unroll
    for (int ks = 0; ks < 4; ++ks) {
      const int off = (t*16 + c) * DH + ks*32 + g*8;
      {
        float4 x = *reinterpret_cast<const float4*>(qp + off);
        float4 y = *reinterpret_cast<const float4*>(qp + off + 4);
        union { unsigned u[4]; bf16x8 f; } un;
        un.u[0] = pk2(x.x, x.y); un.u[1] = pk2(x.z, x.w);
        un.u[2] = pk2(y.x, y.y); un.u[3] = pk2(y.z, y.w);
        qa[t][ks] = un.f;
      }
      {
        float4 x = *reinterpret_cast<const float4*>(kp + off);
        float4 y = *reinterpret_cast<const float4*>(kp + off + 4);
        union { unsigned u[4]; bf16x8 f; } un;
        un.u[0] = pk2(x.x, x.y); un.u[1] = pk2(x.z, x.w);
        un.u[2] = pk2(y.x, y.y); un.u[3] = pk2(y.z, y.w);
        kb[t][ks] = un.f;
      }
    }
  }

  // ---- S = Q K^T over heads: 4 16x16 tiles, K-dim 128
  f32x4 S[2][2];
#pragma unroll
  for (int it = 0; it < 2; ++it)
#pragma unroll
    for (int jt = 0; jt < 2; ++jt) {
      f32x4 acc = (f32x4)0.0f;
#pragma unroll
      for (int ks = 0; ks < 4; ++ks)
        acc = __builtin_amdgcn_mfma_f32_16x16x32_bf16(qa[it][ks], kb[jt][ks], acc, 0, 0, 0);
      S[it][jt] = acc;
    }

  // D-layout: S[it][jt][rr] = S_full[it*16 + g*4 + rr][jt*16 + c]
  // ---- single-pass softmax over 32 cols (row lives in the 16 lanes sharing g)
  float p[2][2][4];
  float inv[2][4];
#pragma unroll
  for (int it = 0; it < 2; ++it) {
    float pm[4], ls[4];
#pragma unroll
    for (int rr = 0; rr < 4; ++rr)
      pm[rr] = fmaxf(S[it][0][rr], S[it][1][rr]) * SCALE;
#pragma unroll
    for (int m = 1; m <= 8; m <<= 1)
#pragma unroll
      for (int rr = 0; rr < 4; ++rr)
        pm[rr] = fmaxf(pm[rr], __shfl_xor(pm[rr], m));
#pragma unroll
    for (int rr = 0; rr < 4; ++rr) ls[rr] = 0.0f;
#pragma unroll
    for (int jt = 0; jt < 2; ++jt)
#pragma unroll
      for (int rr = 0; rr < 4; ++rr) {
        float e = __expf(S[it][jt][rr] * SCALE - pm[rr]);
        p[it][jt][rr] = e;
        ls[rr] += e;
      }
#pragma unroll
    for (int m = 1; m <= 8; m <<= 1)
#pragma unroll
      for (int rr = 0; rr < 4; ++rr)
        ls[rr] += __shfl_xor(ls[rr], m);
#pragma unroll
    for (int rr = 0; rr < 4; ++rr) inv[it][rr] = 1.0f / ls[rr];
  }

  // ---- write normalized P (bf16) to per-wave LDS (D-layout -> row-major [i][j])
#pragma unroll
  for (int it = 0; it < 2; ++it)
#pragma unroll
    for (int jt = 0; jt < 2; ++jt)
#pragma unroll
      for (int rr = 0; rr < 4; ++rr)
        Pl[w][it*16 + g*4 + rr][jt*16 + c] =
            (unsigned short)f2bf(p[it][jt][rr] * inv[it][rr]);

  // ---- read P back as A-frags: lane holds row (it*16+c), j = g*8 .. +7 (K=32)
  bf16x8 pa[2];
  pa[0] = *reinterpret_cast<const bf16x8*>(&Pl[w][c][g*8]);
  pa[1] = *reinterpret_cast<const bf16x8*>(&Pl[w][16 + c][g*8]);

  // ---- O = P V, one K=32 mfma per (it, dt) tile; store immediately
#pragma unroll
  for (int dt = 0; dt < 8; ++dt) {
    float vv[8];
#pragma unroll
    for (int j = 0; j < 8; ++j)
      vv[j] = vp[(g*8 + j) * DH + dt*16 + c];   // V[j][d]: B-frag (n=c, k=g*8+j)
    union { unsigned u[4]; bf16x8 f; } un;
    un.u[0] = pk2(vv[0], vv[1]); un.u[1] = pk2(vv[2], vv[3]);
    un.u[2] = pk2(vv[4], vv[5]); un.u[3] = pk2(vv[6], vv[7]);
#pragma unroll
    for (int it = 0; it < 2; ++it) {
      f32x4 o = __builtin_amdgcn_mfma_f32_16x16x32_bf16(pa[it], un.f, (f32x4)0.0f, 0, 0, 0);
#pragma unroll
      for (int rr = 0; rr < 4; ++rr)
        op[(it*16 + g*4 + rr) * DH + dt*16 + c] = o[rr];
    }
  }
}

extern "C" void kernel_launch(void* const* d_in, const int* in_sizes, int n_in,
                              void* d_out, int out_size, void* d_ws, size_t ws_size,
                              hipStream_t stream) {
  const float* q = (const float*)d_in[0];
  const float* k = (const float*)d_in[1];
  const float* v = (const float*)d_in[2];
  float* o = (float*)d_out;
  // 16384 positions (b=2 x s=8192), 8 waves/block -> 2048 blocks
  hda<<<dim3(2048, 1, 1), dim3(512, 1, 1), 0, stream>>>(q, k, v, o);
}